// Round 16
// baseline (236.667 us; speedup 1.0000x reference)
//
#include <hip/hip_runtime.h>
#include <hip/hip_bf16.h>

#define B_ROWS 65536
#define NA 128
#define D_OUT 1024
#define VBS 128
#define NCHUNK (B_ROWS / VBS)   // 512

typedef __attribute__((ext_vector_type(8))) short bf16x8s;
typedef __attribute__((ext_vector_type(4))) float f32x4;
typedef __attribute__((ext_vector_type(2))) float f32x2;
typedef __attribute__((ext_vector_type(4))) unsigned short u16x4;
typedef __attribute__((ext_vector_type(8))) unsigned short u16x8;

static __device__ __forceinline__ short f2bf(float f) {
    unsigned u = __builtin_bit_cast(unsigned, f);
    u = u + 0x7FFFu + ((u >> 16) & 1u);   // round-to-nearest-even to bf16
    return (short)(u >> 16);
}
static __device__ __forceinline__ float bf2f(unsigned short h) {
    unsigned u = ((unsigned)h) << 16;
    return __builtin_bit_cast(float, u);
}
// packed RNE f32->bf16 pair: 1 VALU op for 2 elements
static __device__ __forceinline__ unsigned cvt_pk_bf16(float a, float b) {
    unsigned r;
    asm("v_cvt_pk_bf16_f32 %0, %1, %2" : "=v"(r) : "v"(a), "v"(b));
    return r;
}

// One block per chunk: compute GBN stats, then write normalized a as bf16.
__global__ void gbn_norm_kernel(const float* __restrict__ a,
                                const float* __restrict__ gamma,
                                const float* __restrict__ beta,
                                unsigned short* __restrict__ ab) {
    int c = blockIdx.x;
    int j = threadIdx.x;            // feature 0..127
    const float* p = a + (size_t)c * (VBS * NA) + j;
    float s = 0.f, s2 = 0.f;
#pragma unroll 8
    for (int r = 0; r < VBS; ++r) {
        float v = p[r * NA];
        s += v; s2 += v * v;
    }
    float mean = s * (1.f / VBS);
    float var  = fmaxf(s2 * (1.f / VBS) - mean * mean, 0.f);   // biased var
    float sc = gamma[j] * rsqrtf(var + 1e-5f);
    float sh = beta[j] - mean * sc;
    unsigned short* o = ab + (size_t)c * (VBS * NA) + j;
#pragma unroll 8
    for (int r = 0; r < VBS; ++r) {
        float v = p[r * NA];
        o[r * NA] = (unsigned short)f2bf(v * sc + sh);
    }
}

// Pack W for the 8-wave/128-col kernel: chunk c = ((w*4+ks)*8+nf)*64 + lane,
// lane=(g*16+q), holding W[w*128 + nf*16 + q][ks*32 + g*8 .. +8].
__global__ void wpack_kernel(const float* __restrict__ W, u16x8* __restrict__ Wp) {
    int c = blockIdx.x * 256 + threadIdx.x;   // 16384 chunks
    int lane = c & 63;
    int nf   = (c >> 6) & 7;
    int ks   = (c >> 9) & 3;
    int w    = (c >> 11) & 7;
    int g = lane >> 4, q = lane & 15;
    const float* src = W + (size_t)(w * 128 + nf * 16 + q) * NA + ks * 32 + g * 8;
    u16x8 h;
#pragma unroll
    for (int i = 0; i < 8; ++i) h[i] = (unsigned short)f2bf(src[i]);
    Wp[c] = h;
}

// One block per 32 rows, 512 threads = 8 waves. Wave w owns ALL 32 rows x
// cols [w*128, w*128+128): per ks, 2 A-fragments (row halves) x 8 W-fragments
// -> 16 MFMAs; acc[2][8] (64 AGPR, same as before) but per-wave VMEM drops
// 84 -> 56 and each 256KB Wp pass serves 32 rows (halved L2 traffic).
// Epilogue identical to R13/R15: *prior (prefetched), bf16 LDS transpose,
// warm-started packed Michelot (ballot+popc count), out = relu(v + tau).
__global__ __launch_bounds__(512, 2) void fused_kernel(
    const unsigned short* __restrict__ ab,
    const float* __restrict__ prior,
    const u16x8* __restrict__ Wp,
    float* __restrict__ out) {

    const int tid  = threadIdx.x;
    const int w    = tid >> 6;        // 0..7  (col block of 128)
    const int lane = tid & 63;
    const int g    = lane >> 4;       // 0..3
    const int q    = lane & 15;       // row within 16-row subtile

    const int r0 = blockIdx.x * 32;

    // ---- prefetch prior into registers (HBM latency overlaps GEMM) ----
    float4 pr[2][8];
#pragma unroll
    for (int rh = 0; rh < 2; ++rh) {
        const float* pb = prior + (size_t)(r0 + rh * 16 + q) * D_OUT + w * 128 + 4 * g;
#pragma unroll
        for (int nf = 0; nf < 8; ++nf) pr[rh][nf] = *(const float4*)(pb + nf * 16);
    }

    f32x4 acc[2][8];
#pragma unroll
    for (int rh = 0; rh < 2; ++rh)
#pragma unroll
        for (int i = 0; i < 8; ++i) acc[rh][i] = (f32x4){0.f, 0.f, 0.f, 0.f};

    // ---- GEMM: y[32 x 1024] = GBN(a)[32 x 128] * W^T (operands swapped) ----
#pragma unroll
    for (int ks = 0; ks < 4; ++ks) {
        const int k0 = ks * 32 + g * 8;
        bf16x8s af0 = *(const bf16x8s*)(ab + (size_t)(r0 + q) * NA + k0);
        bf16x8s af1 = *(const bf16x8s*)(ab + (size_t)(r0 + 16 + q) * NA + k0);

        const bf16x8s* wp = (const bf16x8s*)(Wp + ((size_t)(w * 4 + ks) * 8) * 64 + lane);
#pragma unroll
        for (int nf = 0; nf < 8; ++nf) {
            bf16x8s bf = wp[nf * 64];
            acc[0][nf] = __builtin_amdgcn_mfma_f32_16x16x32_bf16(bf, af0, acc[0][nf], 0, 0, 0);
            acc[1][nf] = __builtin_amdgcn_mfma_f32_16x16x32_bf16(bf, af1, acc[1][nf], 0, 0, 0);
        }
    }

    // ---- multiply by prior (from registers) ----
#pragma unroll
    for (int rh = 0; rh < 2; ++rh)
#pragma unroll
        for (int nf = 0; nf < 8; ++nf) {
            acc[rh][nf][0] *= pr[rh][nf].x; acc[rh][nf][1] *= pr[rh][nf].y;
            acc[rh][nf][2] *= pr[rh][nf].z; acc[rh][nf][3] *= pr[rh][nf].w;
        }

    // ---- transpose through LDS (bf16, padded layout) ----
    __shared__ unsigned short ls[32][1032];   // 32 x (1024+8 pad) = 66 KB
#pragma unroll
    for (int rh = 0; rh < 2; ++rh)
#pragma unroll
        for (int nf = 0; nf < 8; ++nf) {
            uint2 hh;
            hh.x = cvt_pk_bf16(acc[rh][nf][0], acc[rh][nf][1]);
            hh.y = cvt_pk_bf16(acc[rh][nf][2], acc[rh][nf][3]);
            *(uint2*)&ls[rh * 16 + q][w * 128 + nf * 16 + 4 * g] = hh;
        }
    __syncthreads();

    // ---- load this wave's 4 rows as f32x2 pairs: va[4][8] ----
    f32x2 va[4][8];
#pragma unroll
    for (int r = 0; r < 4; ++r) {
        const int row = w * 4 + r;
#pragma unroll
        for (int j = 0; j < 4; ++j) {
            u16x4 hv = *(const u16x4*)&ls[row][j * 256 + lane * 4];
            va[r][2 * j + 0] = (f32x2){bf2f(hv[0]), bf2f(hv[1])};
            va[r][2 * j + 1] = (f32x2){bf2f(hv[2]), bf2f(hv[3])};
        }
    }

    // ---- row maxima (packed tree + wave reduce) -> tau0 = max - 1 ----
    float mx[4];
#pragma unroll
    for (int r = 0; r < 4; ++r) {
        f32x2 m2 = va[r][0];
#pragma unroll
        for (int e = 1; e < 8; ++e) m2 = __builtin_elementwise_max(m2, va[r][e]);
        mx[r] = fmaxf(m2[0], m2[1]);
    }
#pragma unroll
    for (int m = 1; m < 64; m <<= 1) {
#pragma unroll
        for (int r = 0; r < 4; ++r) mx[r] = fmaxf(mx[r], __shfl_xor(mx[r], m));
    }

    float tau[4];
    int   cp[4];
#pragma unroll
    for (int r = 0; r < 4; ++r) { tau[r] = mx[r] - 1.f; cp[r] = -1; }

    // ---- Michelot from the bracket: tau += (F(tau)-1)/C, monotone up ----
#pragma unroll 1
    for (int it = 0; it < 16; ++it) {
        f32x2 t2[4];
#pragma unroll
        for (int r = 0; r < 4; ++r) t2[r] = (f32x2){tau[r], tau[r]};
        f32x2 S2[4];
        int   C[4];
#pragma unroll
        for (int r = 0; r < 4; ++r) { S2[r] = (f32x2){0.f, 0.f}; C[r] = 0; }
#pragma unroll
        for (int e = 0; e < 8; ++e) {
#pragma unroll
            for (int r = 0; r < 4; ++r) {
                f32x2 d = va[r][e] - t2[r];
                S2[r] += __builtin_elementwise_max(d, (f32x2){0.f, 0.f});
                C[r] += (int)__popcll(__ballot(d[0] > 0.f));
                C[r] += (int)__popcll(__ballot(d[1] > 0.f));
            }
        }
        float S[4];
#pragma unroll
        for (int r = 0; r < 4; ++r) S[r] = S2[r][0] + S2[r][1];
#pragma unroll
        for (int m = 1; m < 64; m <<= 1) {
#pragma unroll
            for (int r = 0; r < 4; ++r) S[r] += __shfl_xor(S[r], m);
        }
        bool all_done = true;
#pragma unroll
        for (int r = 0; r < 4; ++r) {
            tau[r] += (S[r] - 1.f) * __builtin_amdgcn_rcpf((float)C[r]);
            all_done = all_done && (C[r] == cp[r]);
            cp[r] = C[r];
        }
        if (all_done) break;
    }

    // ---- output: reference computes relu(x + tau_std) -> ADD tau ----
#pragma unroll
    for (int r = 0; r < 4; ++r) {
        const int row = w * 4 + r;
        f32x2 t2 = (f32x2){tau[r], tau[r]};
        float* ob = out + (size_t)(r0 + row) * D_OUT + lane * 4;
#pragma unroll
        for (int j = 0; j < 4; ++j) {
            f32x2 o0 = __builtin_elementwise_max(va[r][2 * j + 0] + t2, (f32x2){0.f, 0.f});
            f32x2 o1 = __builtin_elementwise_max(va[r][2 * j + 1] + t2, (f32x2){0.f, 0.f});
            float4 o;
            o.x = o0[0]; o.y = o0[1]; o.z = o1[0]; o.w = o1[1];
            *(float4*)(ob + j * 256) = o;
        }
    }
}

extern "C" void kernel_launch(void* const* d_in, const int* in_sizes, int n_in,
                              void* d_out, int out_size, void* d_ws, size_t ws_size,
                              hipStream_t stream) {
    const float* a     = (const float*)d_in[0];
    const float* prior = (const float*)d_in[1];
    const float* gamma = (const float*)d_in[2];
    const float* beta  = (const float*)d_in[3];
    const float* W     = (const float*)d_in[4];
    float* out = (float*)d_out;

    u16x8*          Wp = (u16x8*)d_ws;                            // 256 KB @ 0
    unsigned short* ab = (unsigned short*)((char*)d_ws + 262144); // 16 MB @ 256K

    gbn_norm_kernel<<<NCHUNK, VBS, 0, stream>>>(a, gamma, beta, ab);
    wpack_kernel<<<64, 256, 0, stream>>>(W, Wp);
    fused_kernel<<<B_ROWS / 32, 512, 0, stream>>>(ab, prior, Wp, out);
}